// Round 1
// 206.123 us; speedup vs baseline: 1.1079x; 1.1079x over previous
//
#include <hip/hip_runtime.h>

// CTC loss forward (sum reduction). Shapes fixed: T=1000, B=64, V=512, S=100.
// PRODUCER/CONSUMER fused kernel: one block (4 waves) per batch element b.
//   - Wave 0 (consumer): per chunk, batched 24x ds_read_b32 gather + exp2 +
//     8 recursion steps (linear domain, 2^5/step scale, DPP renorm /16 steps).
//     It NEVER waits on vmcnt - staging stalls are off its critical path.
//   - Waves 1..3 (producers): round-robin DMA staging. Producer p owns chunks
//     c == p (mod 3): issues 16x global_load_lds(16B) for chunk c three
//     windows ahead, s_waitcnt vmcnt(0) one window before consumption.
//   - Sync: ONE raw s_barrier per chunk (NOT __syncthreads - that emits
//     vmcnt(0) and would drain producer DMA queues every chunk).
//   - Buffers: 4 x 8 rows x 2048 B. Window j: buf[j&3] read, buf[(j+1)&3],
//     buf[(j+2)&3] landing, buf[(j+3)&3]=buf[(j-1)&3] being re-issued (freed
//     at barrier j). Exactly 4 live roles -> no overlap.

#define NEGF (-1e30f)

constexpr int CT_T  = 1000;
constexpr int CT_B  = 64;
constexpr int CT_V  = 512;
constexpr int CT_S  = 100;
constexpr int CT_Se = 201;
constexpr float LOG2E = 1.4426950408889634f;
constexpr float LN2   = 0.6931471805599453f;
constexpr float SHIFT = 5.0f;

#if __has_builtin(__builtin_amdgcn_exp2f) && __has_builtin(__builtin_amdgcn_logf)
__device__ __forceinline__ float fexp2(float x) { return __builtin_amdgcn_exp2f(x); }
__device__ __forceinline__ float flog2(float x) { return __builtin_amdgcn_logf(x); }
__device__ __forceinline__ float frcp(float x)  { return __builtin_amdgcn_rcpf(x); }
#else
__device__ __forceinline__ float fexp2(float x) { return exp2f(x); }
__device__ __forceinline__ float flog2(float x) { return log2f(x); }
__device__ __forceinline__ float frcp(float x)  { return 1.0f / x; }
#endif

__device__ __forceinline__ float lae2_b2(float x, float y) {
    float m = fmaxf(x, y);
    float d = fminf(x, y) - m;
    return m + flog2(1.0f + fexp2(d));
}
__device__ __forceinline__ float lae3_b2(float x, float y, float z) {
    float m = fmaxf(fmaxf(x, y), z);
    float s = fexp2(x - m) + fexp2(y - m) + fexp2(z - m);
    return m + flog2(s);
}

// lane l <- lane l-1 (lane 0 <- 0): DPP wave_shr:1, VALU speed.
__device__ __forceinline__ float wave_shr1(float x) {
    return __int_as_float(__builtin_amdgcn_update_dpp(
        0, __float_as_int(x), 0x138, 0xf, 0xf, true));
}
// wave max of NON-NEGATIVE x, all-VALU DPP reduce; uniform via readlane 63.
__device__ __forceinline__ float wave_max_nonneg(float x) {
#define DPPMAX(ctrl) x = fmaxf(x, __int_as_float(__builtin_amdgcn_update_dpp( \
        0, __float_as_int(x), ctrl, 0xf, 0xf, true)))
    DPPMAX(0x111); DPPMAX(0x112); DPPMAX(0x114); DPPMAX(0x118);
    DPPMAX(0x142); DPPMAX(0x143);
#undef DPPMAX
    return __int_as_float(__builtin_amdgcn_readlane(__float_as_int(x), 63));
}

typedef const __attribute__((address_space(1))) unsigned int* as1_uint_ptr;
typedef __attribute__((address_space(3))) unsigned int* as3_uint_ptr;
__device__ __forceinline__ void gld16(const void* g, void* l) {
    __builtin_amdgcn_global_load_lds((as1_uint_ptr)g, (as3_uint_ptr)l, 16, 0, 0);
}

// ---------------- fused recursion, producer/consumer ----------------
__global__ __launch_bounds__(256, 1) void ctc_alpha(
    const float* __restrict__ logp,    // (T, B, V)
    const int*   __restrict__ in_len,
    const int*   __restrict__ tgt,
    const int*   __restrict__ tgt_len,
    float*       __restrict__ loss_ws)
{
    __shared__ float ldsr[4][8][CT_V];   // 64 KiB: 4 bufs x 8 rows x 2048 B

    const int b    = blockIdx.x;
    const int tid  = threadIdx.x;
    const int wv   = tid >> 6;           // 0 = consumer, 1..3 = producers
    const int lane = tid & 63;
    const int Tin  = in_len[b];
    const int Lt   = tgt_len[b];
    const int lim  = 2 * Lt + 1;
    const int* tg  = tgt + b * CT_S;

    const int Kf = (Tin - 1) / 8;        // full chunks
    const int K  = (Tin - 1 + 7) / 8;    // total chunks (K >= 63 for Tin >= 500)

    const int s0 = 4 * lane, s1 = s0 + 1, s3 = s0 + 3;
    const int i1 = min((s1 - 1) >> 1, CT_S - 1);
    const int i3 = min((s3 - 1) >> 1, CT_S - 1);
    const int c1 = tg[i1];
    const int c3 = tg[i3];
    const float sk1 = ((s1 >= 3) && (s1 < CT_Se) && (c1 != tg[max(i1 - 1, 0)])) ? 1.f : 0.f;
    const float sk3 = ((s3 >= 3) && (s3 < CT_Se) && (c3 != tg[max(i3 - 1, 0)])) ? 1.f : 0.f;
    const float m0 = (s0     < lim) ? 1.f : 0.f;
    const float m1 = (s0 + 1 < lim) ? 1.f : 0.f;
    const float m2 = (s0 + 2 < lim) ? 1.f : 0.f;
    const float m3 = (s0 + 3 < lim) ? 1.f : 0.f;

    float a0 = 0.f, a1 = 0.f, a2 = 0.f, a3 = 0.f, pa3 = 0.f;
    if (tid == 0) {
        const float* r0 = logp + (size_t)b * CT_V;
        a0 = fexp2(fmaf(r0[1], LOG2E, SHIFT));
        if (Lt > 0) a1 = fexp2(fmaf(r0[c1], LOG2E, SHIFT));
    }
    float rs = 0.f;   // accumulated renorm log2-scale (wave-uniform)

    auto issue = [&](int k, int buf) {
        const int tb = 1 + 8 * k;
        #pragma unroll
        for (int i = 0; i < 8; ++i) {
            const int t = min(tb + i, CT_T - 1);
            const char* g = (const char*)(logp + ((size_t)t * CT_B + b) * CT_V)
                          + (size_t)lane * 16;
            gld16(g,        &ldsr[buf][i][0]);
            gld16(g + 1024, &ldsr[buf][i][256]);
        }
    };

    auto renorm = [&]() {
        float lm = wave_max_nonneg(fmaxf(fmaxf(a0, a1), fmaxf(a2, a3)));
        if (lm > 0.f) {
            float sc = frcp(lm);
            rs += flog2(lm);
            a0 *= sc; a1 *= sc; a2 *= sc; a3 *= sc;
            pa3 = wave_shr1(a3);
        }
    };

    auto run8 = [&](int buf, int tb, bool guard) {
        // --- batched LDS gather: forced by inline asm (24 ds_read_b32) ---
        // generic->LDS offset: low 32 bits of a __shared__ pointer
        unsigned base = (unsigned)(size_t)(&ldsr[buf][0][0]);
        unsigned ab = base + 4u * 1;
        unsigned a1a = base + 4u * (unsigned)c1;
        unsigned a3a = base + 4u * (unsigned)c3;
        float g0,g1,g2,g3,g4,g5,g6,g7,g8,g9,g10,g11,
              g12,g13,g14,g15,g16,g17,g18,g19,g20,g21,g22,g23;
        asm volatile(
            "ds_read_b32 %0,  %24 offset:0\n\t"
            "ds_read_b32 %1,  %25 offset:0\n\t"
            "ds_read_b32 %2,  %26 offset:0\n\t"
            "ds_read_b32 %3,  %24 offset:2048\n\t"
            "ds_read_b32 %4,  %25 offset:2048\n\t"
            "ds_read_b32 %5,  %26 offset:2048\n\t"
            "ds_read_b32 %6,  %24 offset:4096\n\t"
            "ds_read_b32 %7,  %25 offset:4096\n\t"
            "ds_read_b32 %8,  %26 offset:4096\n\t"
            "ds_read_b32 %9,  %24 offset:6144\n\t"
            "ds_read_b32 %10, %25 offset:6144\n\t"
            "ds_read_b32 %11, %26 offset:6144\n\t"
            "ds_read_b32 %12, %24 offset:8192\n\t"
            "ds_read_b32 %13, %25 offset:8192\n\t"
            "ds_read_b32 %14, %26 offset:8192\n\t"
            "ds_read_b32 %15, %24 offset:10240\n\t"
            "ds_read_b32 %16, %25 offset:10240\n\t"
            "ds_read_b32 %17, %26 offset:10240\n\t"
            "ds_read_b32 %18, %24 offset:12288\n\t"
            "ds_read_b32 %19, %25 offset:12288\n\t"
            "ds_read_b32 %20, %26 offset:12288\n\t"
            "ds_read_b32 %21, %24 offset:14336\n\t"
            "ds_read_b32 %22, %25 offset:14336\n\t"
            "ds_read_b32 %23, %26 offset:14336\n\t"
            "s_waitcnt lgkmcnt(0)"
            : "=&v"(g0), "=&v"(g1), "=&v"(g2), "=&v"(g3), "=&v"(g4), "=&v"(g5),
              "=&v"(g6), "=&v"(g7), "=&v"(g8), "=&v"(g9), "=&v"(g10), "=&v"(g11),
              "=&v"(g12), "=&v"(g13), "=&v"(g14), "=&v"(g15), "=&v"(g16), "=&v"(g17),
              "=&v"(g18), "=&v"(g19), "=&v"(g20), "=&v"(g21), "=&v"(g22), "=&v"(g23)
            : "v"(ab), "v"(a1a), "v"(a3a));

        float eb[8], e1[8], e3[8];
        float gb[24] = {g0,g1,g2,g3,g4,g5,g6,g7,g8,g9,g10,g11,
                        g12,g13,g14,g15,g16,g17,g18,g19,g20,g21,g22,g23};
        #pragma unroll
        for (int i = 0; i < 8; ++i) {
            eb[i] = fexp2(fmaf(gb[3 * i],     LOG2E, SHIFT));
            e1[i] = fexp2(fmaf(gb[3 * i + 1], LOG2E, SHIFT));
            e3[i] = fexp2(fmaf(gb[3 * i + 2], LOG2E, SHIFT));
        }
        #pragma unroll
        for (int i = 0; i < 8; ++i) {
            float ex = eb[i] * m0, ey = e1[i] * m1;
            float ez = eb[i] * m2, ew = e3[i] * m3;
            float n0 = (a0 + pa3) * ex;
            float n1 = fmaf(sk1, pa3, a1 + a0) * ey;
            float n2 = (a2 + a1) * ez;
            float n3 = fmaf(sk3, a1, a3 + a2) * ew;
            if (!guard || (tb + i < Tin)) { a0 = n0; a1 = n1; a2 = n2; a3 = n3; }
            pa3 = wave_shr1(a3);
        }
    };

    // ---- prologue: producers pre-issue chunks 0..2 (chunk c -> producer c%3)
    if (wv) {
        const int p = wv - 1;
        if (p < K) issue(p, p);
        if (p == 0)                      // chunk 0 must be resident at barrier_0
            asm volatile("s_waitcnt vmcnt(0)" ::: "memory");
    }
    __builtin_amdgcn_s_barrier();        // barrier_0

    // ---- main loop: one window per chunk, one raw barrier per window
    for (int j = 0; j < K; ++j) {
        if (wv == 0) {
            if (j < Kf) { run8(j & 3, 0, false); if (j & 1) renorm(); }
            else        run8(j & 3, 1 + 8 * j, true);   // guarded tail chunk
        } else {
            const int p = wv - 1;
            // issue chunk j+3 (owner: (j+3)%3 == j%3) into the buffer freed
            // by chunk j-1 at barrier_j
            if ((j % 3) == p && (j + 3) < K) issue(j + 3, (j + 3) & 3);
            // ensure chunk j+1 resident before barrier_{j+1}; at this point
            // this wave's ONLY outstanding DMAs are chunk j+1's 16 loads
            if (((j + 1) % 3) == p && (j + 1) < K)
                asm volatile("s_waitcnt vmcnt(0)" ::: "memory");
        }
        __builtin_amdgcn_s_barrier();    // barrier_{j+1}
    }

    if (wv) {                            // producers: drain & exit
        asm volatile("s_waitcnt vmcnt(0)" ::: "memory");
        return;
    }

    // ---- consumer epilogue
    const int last = 2 * Lt;
    const int prev = max(last - 1, 0);
    const int lr = last & 3, lidx = last >> 2;
    float av = (lr == 0) ? a0 : (lr == 1) ? a1 : (lr == 2) ? a2 : a3;
    float a_last = __shfl(av, lidx);
    const int pr = prev & 3, pidx = prev >> 2;
    float pv = (pr == 0) ? a0 : (pr == 1) ? a1 : (pr == 2) ? a2 : a3;
    float a_prev = __shfl(pv, pidx);

    float sum = a_last + a_prev;
    float loss = 0.f;
    if (sum > 0.f)
        loss = -(flog2(sum) + rs - SHIFT * (float)Tin) * LN2;
    if (lane == 0) loss_ws[b] = loss;
}

// ---------------- Fallback (log-domain single pass) ----------------
__global__ __launch_bounds__(64) void ctc_alpha_fb(
    const float* __restrict__ logp, const int* __restrict__ in_len,
    const int* __restrict__ tgt, const int* __restrict__ tgt_len,
    float* __restrict__ loss_ws)
{
    const int b = blockIdx.x, lane = threadIdx.x;
    const int Tin = in_len[b], Lt = tgt_len[b];
    const int ext_len = 2 * Lt + 1;
    const int* tg = tgt + b * CT_S;
    const int s0 = 4 * lane, s1 = s0 + 1, s3 = s0 + 3;
    const int i1 = min((s1 - 1) >> 1, CT_S - 1);
    const int i3 = min((s3 - 1) >> 1, CT_S - 1);
    const int c1 = tg[i1], c3 = tg[i3];
    const bool skip1 = (s1 >= 3) && (s1 < CT_Se) && (c1 != tg[max(i1 - 1, 0)]);
    const bool skip3 = (s3 >= 3) && (s3 < CT_Se) && (c3 != tg[max(i3 - 1, 0)]);
    const bool v0 = s0 < ext_len, v1 = s1 < ext_len;
    const bool v2 = (s0 + 2) < ext_len, v3 = s3 < ext_len;
    const float* row0 = logp + (long long)b * CT_V;
    const long long stride = (long long)CT_B * CT_V;
    float a0 = NEGF, a1 = NEGF, a2 = NEGF, a3 = NEGF;
    if (lane == 0) {
        a0 = row0[1] * LOG2E;
        if (ext_len > 1) a1 = row0[c1] * LOG2E;
    }
    float3 E0, E1, E2, E3;
    auto ld = [&](float3& e, int t) {
        int tt = min(t, CT_T - 1);
        const float* r = row0 + (long long)tt * stride;
        e.x = r[1] * LOG2E; e.y = r[c1] * LOG2E; e.z = r[c3] * LOG2E;
    };
    auto step = [&](const float3& e) {
        float pa3 = __shfl_up(a3, 1);
        if (lane == 0) pa3 = NEGF;
        float z1 = skip1 ? pa3 : NEGF;
        float z3 = skip3 ? a1 : NEGF;
        float n0 = v0 ? lae2_b2(a0, pa3)    + e.x : NEGF;
        float n1 = v1 ? lae3_b2(a1, a0, z1) + e.y : NEGF;
        float n2 = v2 ? lae2_b2(a2, a1)     + e.x : NEGF;
        float n3 = v3 ? lae3_b2(a3, a2, z3) + e.z : NEGF;
        a0 = n0; a1 = n1; a2 = n2; a3 = n3;
    };
    ld(E0, 1); ld(E1, 2); ld(E2, 3); ld(E3, 4);
    for (int t = 1; t < Tin; t += 4) {
        step(E0); ld(E0, t + 4);
        if (t + 1 < Tin) { step(E1); ld(E1, t + 5); }
        if (t + 2 < Tin) { step(E2); ld(E2, t + 6); }
        if (t + 3 < Tin) { step(E3); ld(E3, t + 7); }
    }
    const int last = 2 * Lt, prev = max(last - 1, 0);
    const int lr = last & 3, lidx = last >> 2;
    float av = (lr == 0) ? a0 : (lr == 1) ? a1 : (lr == 2) ? a2 : a3;
    float a_last = __shfl(av, lidx);
    const int pr = prev & 3, pidx = prev >> 2;
    float pv = (pr == 0) ? a0 : (pr == 1) ? a1 : (pr == 2) ? a2 : a3;
    float a_prev = __shfl(pv, pidx);
    float loglik = lae2_b2(a_last, a_prev) * LN2;
    float loss = (loglik < 0.5f * NEGF) ? 0.0f : -loglik;
    if (lane == 0) loss_ws[b] = loss;
}

__global__ __launch_bounds__(64) void ctc_sum(const float* __restrict__ loss_ws,
                                              float* __restrict__ out)
{
    float v = loss_ws[threadIdx.x];
    #pragma unroll
    for (int o = 32; o > 0; o >>= 1) v += __shfl_down(v, o);
    if (threadIdx.x == 0) out[0] = v;
}

extern "C" void kernel_launch(void* const* d_in, const int* in_sizes, int n_in,
                              void* d_out, int out_size, void* d_ws, size_t ws_size,
                              hipStream_t stream) {
    const float* logp    = (const float*)d_in[0];
    const int*   in_len  = (const int*)d_in[1];
    const int*   tgt     = (const int*)d_in[2];
    const int*   tgt_len = (const int*)d_in[3];
    float* out = (float*)d_out;
    float* loss_ws = (float*)d_ws;   // needs only 256 B

    if (ws_size >= 256 * sizeof(float)) {
        hipLaunchKernelGGL(ctc_alpha, dim3(CT_B), dim3(256), 0, stream,
                           logp, in_len, tgt, tgt_len, loss_ws);
    } else {
        hipLaunchKernelGGL(ctc_alpha_fb, dim3(CT_B), dim3(64), 0, stream,
                           logp, in_len, tgt, tgt_len, loss_ws);
    }
    hipLaunchKernelGGL(ctc_sum, dim3(1), dim3(64), 0, stream, loss_ws, out);
}